// Round 4
// baseline (4717.694 us; speedup 1.0000x reference)
//
#include <hip/hip_runtime.h>
#include <math.h>

typedef unsigned int uint32;
typedef unsigned short ushort;

typedef __bf16 bf16x8 __attribute__((ext_vector_type(8)));
typedef float f32x4 __attribute__((ext_vector_type(4)));

#define DEV static __device__ __forceinline__

DEV float bf2f(ushort u){ return __builtin_bit_cast(float, ((uint32)u) << 16); }
DEV ushort f2bf(float f){
  uint32 i = __builtin_bit_cast(uint32, f);
  uint32 r = i + 0x7fffu + ((i >> 16) & 1u);   // RNE
  return (ushort)(r >> 16);
}
DEV float wsum(float v){
  #pragma unroll
  for (int off = 32; off > 0; off >>= 1) v += __shfl_xor(v, off);
  return v;
}

// ================= diagnostics =================
__global__ void k_flaginit(int* flags){ if (threadIdx.x==0 && blockIdx.x==0) *flags = 1000; }

__global__ void k_detect(const ushort* pe, const ushort* n1g, int* dt, int* flags){
  if (threadIdx.x==0 && blockIdx.x==0){
    int isb = (pe[1]==0x3F80u && n1g[0]==0x3F80u) ? 1 : 0;
    int isf = (pe[1]==0u && pe[3]==0x3F80u && n1g[0]==0u && n1g[1]==0x3F80u) ? 1 : 0;
    *dt = isb ? 1 : 0;
    if (!isb && !isf) atomicMin(flags, 0);
  }
}

__global__ __launch_bounds__(256) void k_cvt(const void* src, ushort* dst, int n, const int* dt){
  __shared__ int sdt;
  if (threadIdx.x==0) sdt = *dt;
  __syncthreads();
  int i = blockIdx.x*256 + threadIdx.x;
  if (i >= n) return;
  dst[i] = sdt ? ((const ushort*)src)[i] : f2bf(((const float*)src)[i]);
}

__global__ __launch_bounds__(256) void k_checkbf(const ushort* __restrict__ p, size_t n, int stage, int* flags){
  size_t i = (size_t)blockIdx.x*256 + threadIdx.x;
  size_t st = (size_t)gridDim.x*256;
  int bad = 0;
  for (; i < n; i += st){
    uint32 e = (p[i] >> 7) & 0xffu;
    if (e >= 0xC0u) bad = 1;
  }
  if (bad) atomicMin(flags, stage);
}
__global__ __launch_bounds__(256) void k_checkf32(const float* __restrict__ p, size_t n, int stage, int* flags){
  size_t i = (size_t)blockIdx.x*256 + threadIdx.x;
  size_t st = (size_t)gridDim.x*256;
  int bad = 0;
  for (; i < n; i += st){
    float v = p[i];
    if (v != v || fabsf(v) > 1e10f) bad = 1;
  }
  if (bad) atomicMin(flags, stage);
}
__global__ __launch_bounds__(256) void k_checkout(const void* out, int n, int stage, int* flags, const int* dtp){
  int i = blockIdx.x*256 + threadIdx.x;
  if (i >= n) return;
  float v = (*dtp) ? bf2f(((const ushort*)out)[i]) : ((const float*)out)[i];
  if (v != v || fabsf(v) > 1e10f) atomicMin(flags, stage);
}
__global__ __launch_bounds__(256) void k_finalize(void* out, int n, const int* flags, const int* dtp){
  int i = blockIdx.x*256 + threadIdx.x;
  if (i >= n) return;
  int f = *flags;
  if (f >= 1000) return;
  float code = 100.f * (float)(f + 1);
  if (*dtp) ((ushort*)out)[i] = f2bf(code);
  else      ((float*)out)[i]  = code;
}

// ================= pipeline =================

__global__ __launch_bounds__(256) void k_transpose(const ushort* __restrict__ src, int ld_src,
    int R, int C, ushort* __restrict__ dst, int ld_dst, int RP)
{
  __shared__ ushort tile[32][33];
  int tx = threadIdx.x & 31, ty = threadIdx.x >> 5;
  int rb = blockIdx.x * 32, cb = blockIdx.y * 32;
  #pragma unroll
  for (int i = 0; i < 4; i++){
    int r = rb + ty + i*8, c = cb + tx;
    ushort v = 0;
    if (r < R && c < C) v = src[(size_t)r*ld_src + c];
    tile[ty + i*8][tx] = v;
  }
  __syncthreads();
  #pragma unroll
  for (int i = 0; i < 4; i++){
    int c = cb + ty + i*8, r = rb + tx;
    if (c < C && r < RP) dst[(size_t)c*ld_dst + r] = tile[tx][ty + i*8];
  }
}

__global__ __launch_bounds__(256) void k_gate(const void* __restrict__ mfv,
    const ushort* __restrict__ gW, const ushort* __restrict__ gb, float* __restrict__ gate,
    const int* dtp)
{
  int n = blockIdx.x, tid = threadIdx.x;
  __shared__ int sdt;
  __shared__ float mkt[64];
  __shared__ float red[256];
  if (tid == 0) sdt = *dtp;
  __syncthreads();
  if (tid < 64){
    size_t idx = ((size_t)n*64 + 63)*64 + tid;
    mkt[tid] = sdt ? bf2f(((const ushort*)mfv)[idx]) : ((const float*)mfv)[idx];
  }
  __syncthreads();
  float lg = -1e30f;
  if (tid < 158){
    float a = bf2f(gb[tid]);
    #pragma unroll 8
    for (int d = 0; d < 64; d++) a += mkt[d] * bf2f(gW[d*158 + tid]);
    lg = a;
  }
  red[tid] = lg; __syncthreads();
  for (int s = 128; s > 0; s >>= 1){ if (tid < s) red[tid] = fmaxf(red[tid], red[tid+s]); __syncthreads(); }
  float mx = red[0]; __syncthreads();
  float p = (tid < 158) ? __expf(lg - mx) : 0.f;
  red[tid] = p; __syncthreads();
  for (int s = 128; s > 0; s >>= 1){ if (tid < s) red[tid] += red[tid+s]; __syncthreads(); }
  float inv = 158.f / red[0];
  if (tid < 158) gate[(size_t)n*158 + tid] = p * inv;
}

// Ag[row][d] = sf[rowoff+row][d] * gate_c[row>>6][d]; K padded 158->160
__global__ __launch_bounds__(256) void k_ag(const void* __restrict__ sfv, size_t rowoff,
    const float* __restrict__ gate_c, ushort* __restrict__ Ag, int total, const int* dtp)
{
  __shared__ int sdt;
  if (threadIdx.x == 0) sdt = *dtp;
  __syncthreads();
  int idx = blockIdx.x*256 + threadIdx.x;
  if (idx >= total) return;
  int row = idx / 160;
  int d = idx - row*160;
  float v = 0.f;
  if (d < 158){
    int n = row >> 6;
    size_t si = (rowoff + (size_t)row)*158 + d;
    float s = sdt ? bf2f(((const ushort*)sfv)[si]) : ((const float*)sfv)[si];
    v = s * gate_c[(size_t)n*158 + d];
  }
  Ag[idx] = f2bf(v);
}

template<int BM, int BN>
__global__ __launch_bounds__(256) void k_gemm(
    const ushort* __restrict__ A, int lda,
    const ushort* __restrict__ WT, int ldw,
    ushort* __restrict__ C, int ldc,
    const ushort* __restrict__ bias,
    const ushort* __restrict__ resid, int ldr,
    const ushort* __restrict__ pe,
    float scale, int relu, int K)
{
  __shared__ ushort As[BM*40];
  __shared__ ushort Bs[BN*40];

  const int tid = threadIdx.x;
  const int wave = tid >> 6, lane = tid & 63;
  const int quad = lane >> 4, l16 = lane & 15;
  constexpr int WC = BN/64;
  const int wr = wave / WC, wc = wave % WC;
  const int m0 = blockIdx.x * BM, n0 = blockIdx.y * BN;

  f32x4 acc[4][4];
  #pragma unroll
  for (int i = 0; i < 4; i++)
    #pragma unroll
    for (int j = 0; j < 4; j++)
      acc[i][j] = f32x4{0.f, 0.f, 0.f, 0.f};

  for (int k0 = 0; k0 < K; k0 += 32){
    __syncthreads();
    #pragma unroll
    for (int i = 0; i < BM/64; i++){
      int ch = tid + i*256;
      int r = ch >> 2, cw = (ch & 3)*8;
      *reinterpret_cast<uint4*>(&As[r*40 + cw]) =
        *reinterpret_cast<const uint4*>(A + (size_t)(m0+r)*lda + k0 + cw);
    }
    #pragma unroll
    for (int i = 0; i < BN/64; i++){
      int ch = tid + i*256;
      int r = ch >> 2, cw = (ch & 3)*8;
      *reinterpret_cast<uint4*>(&Bs[r*40 + cw]) =
        *reinterpret_cast<const uint4*>(WT + (size_t)(n0+r)*ldw + k0 + cw);
    }
    __syncthreads();
    bf16x8 af[4], bfr[4];
    #pragma unroll
    for (int t = 0; t < 4; t++){
      af[t]  = *reinterpret_cast<const bf16x8*>(&As[(wr*64 + t*16 + l16)*40 + quad*8]);
      bfr[t] = *reinterpret_cast<const bf16x8*>(&Bs[(wc*64 + t*16 + l16)*40 + quad*8]);
    }
    #pragma unroll
    for (int mt = 0; mt < 4; mt++)
      #pragma unroll
      for (int nt = 0; nt < 4; nt++)
        acc[mt][nt] = __builtin_amdgcn_mfma_f32_16x16x32_bf16(af[mt], bfr[nt], acc[mt][nt], 0, 0, 0);
  }

  #pragma unroll
  for (int mt = 0; mt < 4; mt++){
    #pragma unroll
    for (int nt = 0; nt < 4; nt++){
      int col = n0 + wc*64 + nt*16 + l16;
      #pragma unroll
      for (int r = 0; r < 4; r++){
        int row = m0 + wr*64 + mt*16 + quad*4 + r;
        float v = acc[mt][nt][r] * scale;
        if (bias)  v += bf2f(bias[col]);
        if (pe)    v += bf2f(pe[(row & 63)*256 + col]);
        if (relu)  v = fmaxf(v, 0.f);
        if (resid) v += bf2f(resid[(size_t)row*ldr + col]);
        C[(size_t)row*ldc + col] = f2bf(v);
      }
    }
  }
}

__global__ __launch_bounds__(256) void k_ln(const ushort* __restrict__ x,
    const ushort* __restrict__ g, const ushort* __restrict__ b, ushort* __restrict__ y)
{
  int row = blockIdx.x*4 + (threadIdx.x >> 6);
  int lane = threadIdx.x & 63;
  ushort4 u = *reinterpret_cast<const ushort4*>(x + (size_t)row*256 + lane*4);
  float v0 = bf2f(u.x), v1 = bf2f(u.y), v2 = bf2f(u.z), v3 = bf2f(u.w);
  float s = wsum(v0+v1+v2+v3);
  float q = wsum(v0*v0+v1*v1+v2*v2+v3*v3);
  float mean = s * (1.f/256.f);
  float var  = fmaxf(q * (1.f/256.f) - mean*mean, 0.f);
  float rs = rsqrtf(var + 1e-5f);
  ushort4 gg = *reinterpret_cast<const ushort4*>(g + lane*4);
  ushort4 bb = *reinterpret_cast<const ushort4*>(b + lane*4);
  ushort4 o;
  o.x = f2bf((v0-mean)*rs*bf2f(gg.x) + bf2f(bb.x));
  o.y = f2bf((v1-mean)*rs*bf2f(gg.y) + bf2f(bb.y));
  o.z = f2bf((v2-mean)*rs*bf2f(gg.z) + bf2f(bb.z));
  o.w = f2bf((v3-mean)*rs*bf2f(gg.w) + bf2f(bb.w));
  *reinterpret_cast<ushort4*>(y + (size_t)row*256 + lane*4) = o;
}

__global__ __launch_bounds__(64) void k_tattn(
    const ushort* __restrict__ q, const ushort* __restrict__ k,
    const ushort* __restrict__ v, ushort* __restrict__ xnxt)
{
  int n = blockIdx.x >> 2, h = blockIdx.x & 3;
  int lane = threadIdx.x;
  int quad = lane >> 4, l16 = lane & 15;
  __shared__ ushort Pl[64*72];
  __shared__ ushort Vt[64*72];
  size_t base = ((size_t)n*64)*256 + (size_t)h*64;

  f32x4 accs[4][4];
  #pragma unroll
  for (int i = 0; i < 4; i++)
    #pragma unroll
    for (int j = 0; j < 4; j++)
      accs[i][j] = f32x4{0.f, 0.f, 0.f, 0.f};

  #pragma unroll
  for (int ks = 0; ks < 64; ks += 32){
    bf16x8 qf[4], kf[4];
    #pragma unroll
    for (int tt = 0; tt < 4; tt++){
      qf[tt] = *reinterpret_cast<const bf16x8*>(q + base + (size_t)(tt*16 + l16)*256 + ks + quad*8);
      kf[tt] = *reinterpret_cast<const bf16x8*>(k + base + (size_t)(tt*16 + l16)*256 + ks + quad*8);
    }
    #pragma unroll
    for (int mt = 0; mt < 4; mt++)
      #pragma unroll
      for (int nt = 0; nt < 4; nt++)
        accs[mt][nt] = __builtin_amdgcn_mfma_f32_16x16x32_bf16(qf[mt], kf[nt], accs[mt][nt], 0, 0, 0);
  }

  for (int s = 0; s < 64; s++)
    Vt[lane*72 + s] = v[base + (size_t)s*256 + lane];

  #pragma unroll
  for (int mt = 0; mt < 4; mt++){
    #pragma unroll
    for (int r = 0; r < 4; r++){
      float a0 = accs[mt][0][r], a1 = accs[mt][1][r], a2 = accs[mt][2][r], a3 = accs[mt][3][r];
      float mx = fmaxf(fmaxf(a0, a1), fmaxf(a2, a3));
      #pragma unroll
      for (int off = 1; off < 16; off <<= 1) mx = fmaxf(mx, __shfl_xor(mx, off));
      float e0 = __expf(a0-mx), e1 = __expf(a1-mx), e2 = __expf(a2-mx), e3 = __expf(a3-mx);
      float sum = e0+e1+e2+e3;
      #pragma unroll
      for (int off = 1; off < 16; off <<= 1) sum += __shfl_xor(sum, off);
      float inv = 1.f/sum;
      int t = mt*16 + quad*4 + r;
      Pl[t*72 +  0 + l16] = f2bf(e0*inv);
      Pl[t*72 + 16 + l16] = f2bf(e1*inv);
      Pl[t*72 + 32 + l16] = f2bf(e2*inv);
      Pl[t*72 + 48 + l16] = f2bf(e3*inv);
    }
  }
  __syncthreads();

  f32x4 acco[4][4];
  #pragma unroll
  for (int i = 0; i < 4; i++)
    #pragma unroll
    for (int j = 0; j < 4; j++)
      acco[i][j] = f32x4{0.f, 0.f, 0.f, 0.f};

  #pragma unroll
  for (int ks = 0; ks < 64; ks += 32){
    bf16x8 pf[4], vf[4];
    #pragma unroll
    for (int tt = 0; tt < 4; tt++){
      pf[tt] = *reinterpret_cast<const bf16x8*>(&Pl[(tt*16 + l16)*72 + ks + quad*8]);
      vf[tt] = *reinterpret_cast<const bf16x8*>(&Vt[(tt*16 + l16)*72 + ks + quad*8]);
    }
    #pragma unroll
    for (int mt = 0; mt < 4; mt++)
      #pragma unroll
      for (int nt = 0; nt < 4; nt++)
        acco[mt][nt] = __builtin_amdgcn_mfma_f32_16x16x32_bf16(pf[mt], vf[nt], acco[mt][nt], 0, 0, 0);
  }

  #pragma unroll
  for (int mt = 0; mt < 4; mt++)
    #pragma unroll
    for (int nt = 0; nt < 4; nt++)
      #pragma unroll
      for (int r = 0; r < 4; r++){
        int t = mt*16 + quad*4 + r, d = nt*16 + l16;
        size_t g = base + (size_t)t*256 + d;
        xnxt[g] = f2bf(bf2f(xnxt[g]) + acco[mt][nt][r]);
      }
}

__global__ __launch_bounds__(256) void k_lamz(const ushort* __restrict__ h,
    const ushort* __restrict__ x2, float* __restrict__ z)
{
  int n = blockIdx.x, tid = threadIdx.x, wave = tid >> 6, lane = tid & 63;
  __shared__ float hl[256];
  __shared__ float dotv[64];
  __shared__ float lamv[64];
  hl[tid] = bf2f(h[((size_t)n*64 + 63)*256 + tid]);
  __syncthreads();
  float h0 = hl[lane*4], h1 = hl[lane*4+1], h2 = hl[lane*4+2], h3 = hl[lane*4+3];
  for (int tt = 0; tt < 16; tt++){
    int t = wave*16 + tt;
    ushort4 u = *reinterpret_cast<const ushort4*>(h + ((size_t)n*64 + t)*256 + lane*4);
    float p = bf2f(u.x)*h0 + bf2f(u.y)*h1 + bf2f(u.z)*h2 + bf2f(u.w)*h3;
    p = wsum(p);
    if (lane == 0) dotv[t] = p;
  }
  __syncthreads();
  if (wave == 0){
    float vv = dotv[lane];
    float mx = vv;
    #pragma unroll
    for (int off = 32; off > 0; off >>= 1) mx = fmaxf(mx, __shfl_xor(mx, off));
    float e = __expf(vv - mx);
    float s = wsum(e);
    lamv[lane] = e / s;
  }
  __syncthreads();
  float acc = 0.f;
  for (int t = 0; t < 64; t++) acc += lamv[t] * bf2f(x2[((size_t)n*64 + t)*256 + tid]);
  z[(size_t)n*256 + tid] = acc;
}

__global__ __launch_bounds__(64) void k_prep(const float* __restrict__ z,
    const int* __restrict__ ids, const ushort* __restrict__ emb,
    const ushort* __restrict__ g1, const ushort* __restrict__ b1,
    const ushort* __restrict__ g2, const ushort* __restrict__ b2,
    ushort* __restrict__ zn, ushort* __restrict__ qkin)
{
  int n = blockIdx.x, lane = threadIdx.x;
  float4 v = *reinterpret_cast<const float4*>(z + (size_t)n*256 + lane*4);
  float s = wsum(v.x+v.y+v.z+v.w);
  float q = wsum(v.x*v.x+v.y*v.y+v.z*v.z+v.w*v.w);
  float mean = s*(1.f/256.f);
  float var = fmaxf(q*(1.f/256.f) - mean*mean, 0.f);
  float rs = rsqrtf(var + 1e-5f);
  ushort4 gg = *reinterpret_cast<const ushort4*>(g1 + lane*4);
  ushort4 bb = *reinterpret_cast<const ushort4*>(b1 + lane*4);
  ushort4 o;
  o.x = f2bf((v.x-mean)*rs*bf2f(gg.x) + bf2f(bb.x));
  o.y = f2bf((v.y-mean)*rs*bf2f(gg.y) + bf2f(bb.y));
  o.z = f2bf((v.z-mean)*rs*bf2f(gg.z) + bf2f(bb.z));
  o.w = f2bf((v.w-mean)*rs*bf2f(gg.w) + bf2f(bb.w));
  *reinterpret_cast<ushort4*>(zn + (size_t)n*256 + lane*4) = o;
  *reinterpret_cast<ushort4*>(qkin + (size_t)n*288 + lane*4) = o;
  int id = ids[n];
  float ev = (lane < 32) ? bf2f(emb[(size_t)id*32 + lane]) : 0.f;
  float se = ev, sq = ev*ev;
  #pragma unroll
  for (int off = 1; off < 32; off <<= 1){ se += __shfl_xor(se, off); sq += __shfl_xor(sq, off); }
  if (lane < 32){
    float m2 = se*(1.f/32.f);
    float va = fmaxf(sq*(1.f/32.f) - m2*m2, 0.f);
    float r2 = rsqrtf(va + 1e-5f);
    qkin[(size_t)n*288 + 256 + lane] = f2bf((ev-m2)*r2*bf2f(g2[lane]) + bf2f(b2[lane]));
  }
}

DEV void unpack2(uint32 w, float& lo, float& hi){ lo = bf2f((ushort)(w & 0xffffu)); hi = bf2f((ushort)(w >> 16)); }
DEV uint32 pack2(float lo, float hi){ return (uint32)f2bf(lo) | ((uint32)f2bf(hi) << 16); }

__global__ __launch_bounds__(256) void k_softmax4096(ushort* __restrict__ S)
{
  size_t row = blockIdx.x;
  ushort* p = S + row*4096;
  int tid = threadIdx.x;
  __shared__ float red[256];
  uint4 a = reinterpret_cast<const uint4*>(p)[tid*2];
  uint4 b = reinterpret_cast<const uint4*>(p)[tid*2 + 1];
  float vals[16];
  unpack2(a.x, vals[0], vals[1]);   unpack2(a.y, vals[2], vals[3]);
  unpack2(a.z, vals[4], vals[5]);   unpack2(a.w, vals[6], vals[7]);
  unpack2(b.x, vals[8], vals[9]);   unpack2(b.y, vals[10], vals[11]);
  unpack2(b.z, vals[12], vals[13]); unpack2(b.w, vals[14], vals[15]);
  float mx = vals[0];
  #pragma unroll
  for (int i = 1; i < 16; i++) mx = fmaxf(mx, vals[i]);
  red[tid] = mx; __syncthreads();
  for (int s = 128; s > 0; s >>= 1){ if (tid < s) red[tid] = fmaxf(red[tid], red[tid+s]); __syncthreads(); }
  float M = red[0]; __syncthreads();
  float ssum = 0.f;
  #pragma unroll
  for (int i = 0; i < 16; i++){ vals[i] = __expf(vals[i] - M); ssum += vals[i]; }
  red[tid] = ssum; __syncthreads();
  for (int s = 128; s > 0; s >>= 1){ if (tid < s) red[tid] += red[tid+s]; __syncthreads(); }
  float inv = 1.f / red[0];
  uint4 oa, ob;
  oa.x = pack2(vals[0]*inv, vals[1]*inv);   oa.y = pack2(vals[2]*inv, vals[3]*inv);
  oa.z = pack2(vals[4]*inv, vals[5]*inv);   oa.w = pack2(vals[6]*inv, vals[7]*inv);
  ob.x = pack2(vals[8]*inv, vals[9]*inv);   ob.y = pack2(vals[10]*inv, vals[11]*inv);
  ob.z = pack2(vals[12]*inv, vals[13]*inv); ob.w = pack2(vals[14]*inv, vals[15]*inv);
  reinterpret_cast<uint4*>(p)[tid*2] = oa;
  reinterpret_cast<uint4*>(p)[tid*2 + 1] = ob;
}

__global__ __launch_bounds__(64) void k_decode(const ushort* __restrict__ xv,
    const ushort* __restrict__ dW, const ushort* __restrict__ db, void* out, const int* dtp)
{
  int n = blockIdx.x, lane = threadIdx.x;
  ushort4 u = *reinterpret_cast<const ushort4*>(xv + (size_t)n*256 + lane*4);
  ushort4 w = *reinterpret_cast<const ushort4*>(dW + lane*4);
  float acc = bf2f(u.x)*bf2f(w.x) + bf2f(u.y)*bf2f(w.y) + bf2f(u.z)*bf2f(w.z) + bf2f(u.w)*bf2f(w.w);
  acc = wsum(acc);
  if (lane == 0){
    float r = acc + bf2f(db[0]);
    if (*dtp) ((ushort*)out)[n] = f2bf(r);
    else      ((float*)out)[n]  = r;
  }
}

extern "C" void kernel_launch(void* const* d_in, const int* in_sizes, int n_in,
                              void* d_out, int out_size, void* d_ws, size_t ws_size,
                              hipStream_t stream)
{
  (void)in_sizes; (void)n_in; (void)out_size;
  const int*  ids = (const int*)d_in[0];
  const void* sf  = d_in[1];
  const void* mf  = d_in[2];

  auto padsz = [](size_t b)->size_t{ return (b + 255) & ~(size_t)255; };
  auto totalBytes = [&](int NCp, int SBp)->size_t{
    size_t MCp = (size_t)NCp*64, t = 0;
    t += 4*padsz(MCp*256*2);
    t += padsz(MCp*160*2);
    t += padsz((size_t)SBp*4096*2);
    t += padsz((size_t)4096*158*4);
    t += padsz((size_t)4096*256*4);
    t += 8*padsz((size_t)4096*256*2);
    t += padsz((size_t)4096*288*2);
    t += padsz((size_t)64*4096*2);
    t += (size_t)6*1024*1024;            // converted weights + transposes + flags + slop
    return t;
  };
  int NC = 64, SB = 512;
  if      (totalBytes(256,2048) <= ws_size){ NC = 256; SB = 2048; }
  else if (totalBytes(128,1024) <= ws_size){ NC = 128; SB = 1024; }
  const int NCHUNK = 4096 / NC;
  const int MC = NC * 64;
  const int NSB = 4096 / SB;

  char* ws = (char*)d_ws;
  size_t off = 0;
  auto alloc = [&](size_t bytes)->char*{ char* p = ws + off; off += (bytes + 255) & ~(size_t)255; return p; };
  int* flags = (int*)alloc(256);
  int* dt    = (int*)alloc(256);
  ushort* C0 = (ushort*)alloc((size_t)MC*256*2);
  ushort* C1 = (ushort*)alloc((size_t)MC*256*2);
  ushort* C2 = (ushort*)alloc((size_t)MC*256*2);
  ushort* C3 = (ushort*)alloc((size_t)MC*256*2);
  ushort* Ag = (ushort*)alloc((size_t)MC*160*2);
  ushort* scoresB = (ushort*)alloc((size_t)SB*4096*2);
  float*  gate = (float*)alloc((size_t)4096*158*4);
  float*  z    = (float*)alloc((size_t)4096*256*4);
  ushort* zn   = (ushort*)alloc((size_t)4096*256*2);
  ushort* q2   = (ushort*)alloc((size_t)4096*256*2);
  ushort* k2   = (ushort*)alloc((size_t)4096*256*2);
  ushort* v2   = (ushort*)alloc((size_t)4096*256*2);
  ushort* xt2  = (ushort*)alloc((size_t)4096*256*2);
  ushort* n3   = (ushort*)alloc((size_t)4096*256*2);
  ushort* h2   = (ushort*)alloc((size_t)4096*256*2);
  ushort* xv   = (ushort*)alloc((size_t)4096*256*2);
  ushort* qkin = (ushort*)alloc((size_t)4096*288*2);
  ushort* v2Th = (ushort*)alloc((size_t)64*4096*2);

  auto cvalloc = [&](int n)->ushort*{ return (ushort*)alloc((size_t)n*2); };
  ushort* gWc   = cvalloc(64*158);
  ushort* gbc   = cvalloc(158);
  ushort* embc  = cvalloc(256*32);
  ushort* projWc= cvalloc(158*256);
  ushort* projbc= cvalloc(256);
  ushort* pec   = cvalloc(100*256);
  ushort* taqWc = cvalloc(65536);
  ushort* takWc = cvalloc(65536);
  ushort* tavWc = cvalloc(65536);
  ushort* n1gc  = cvalloc(256);
  ushort* n1bc  = cvalloc(256);
  ushort* n2gc  = cvalloc(256);
  ushort* n2bc  = cvalloc(256);
  ushort* f1Wc  = cvalloc(65536);
  ushort* f1bc  = cvalloc(256);
  ushort* f2Wc  = cvalloc(65536);
  ushort* f2bc  = cvalloc(256);
  ushort* aggWc = cvalloc(65536);
  ushort* saqWc = cvalloc(288*256);
  ushort* sakWc = cvalloc(288*256);
  ushort* savWc = cvalloc(65536);
  ushort* sn1gc = cvalloc(256);
  ushort* sn1bc = cvalloc(256);
  ushort* sn2gc = cvalloc(32);
  ushort* sn2bc = cvalloc(32);
  ushort* sn3gc = cvalloc(256);
  ushort* sn3bc = cvalloc(256);
  ushort* sf1Wc = cvalloc(65536);
  ushort* sf1bc = cvalloc(256);
  ushort* sf2Wc = cvalloc(65536);
  ushort* sf2bc = cvalloc(256);
  ushort* decWc = cvalloc(256);
  ushort* decbc = cvalloc(1);
  ushort* projWT = cvalloc(256*160);
  ushort* taqWT  = cvalloc(65536);
  ushort* takWT  = cvalloc(65536);
  ushort* tavWT  = cvalloc(65536);
  ushort* f1WT   = cvalloc(65536);
  ushort* f2WT   = cvalloc(65536);
  ushort* aggWT  = cvalloc(65536);
  ushort* savWT  = cvalloc(65536);
  ushort* sf1WT  = cvalloc(65536);
  ushort* sf2WT  = cvalloc(65536);
  ushort* saqWT  = cvalloc(256*288);
  ushort* sakWT  = cvalloc(256*288);

  dim3 b256(256), b64(64);
  auto tg = [](int RP, int C){ return dim3((RP+31)/32, (C+31)/32); };

  k_flaginit<<<1, 64, 0, stream>>>(flags);
  k_detect<<<1, 64, 0, stream>>>((const ushort*)d_in[8], (const ushort*)d_in[12], dt, flags);

  auto cv = [&](int idx, ushort* dst, int n){
    k_cvt<<<(n+255)/256, b256, 0, stream>>>(d_in[idx], dst, n, dt);
  };
  cv(3,  gWc,   64*158);  cv(4,  gbc,   158);     cv(5,  embc,  256*32);
  cv(6,  projWc,158*256); cv(7,  projbc,256);     cv(8,  pec,   100*256);
  cv(9,  taqWc, 65536);   cv(10, takWc, 65536);   cv(11, tavWc, 65536);
  cv(12, n1gc,  256);     cv(13, n1bc,  256);     cv(14, n2gc,  256);
  cv(15, n2bc,  256);     cv(16, f1Wc,  65536);   cv(17, f1bc,  256);
  cv(18, f2Wc,  65536);   cv(19, f2bc,  256);     cv(20, aggWc, 65536);
  cv(21, saqWc, 288*256); cv(22, sakWc, 288*256); cv(23, savWc, 65536);
  cv(24, sn1gc, 256);     cv(25, sn1bc, 256);     cv(26, sn2gc, 32);
  cv(27, sn2bc, 32);      cv(28, sn3gc, 256);     cv(29, sn3bc, 256);
  cv(30, sf1Wc, 65536);   cv(31, sf1bc, 256);     cv(32, sf2Wc, 65536);
  cv(33, sf2bc, 256);     cv(34, decWc, 256);     cv(35, decbc, 1);

  k_transpose<<<tg(160,256), b256, 0, stream>>>(projWc, 256, 158, 256, projWT, 160, 160);
  k_transpose<<<tg(256,256), b256, 0, stream>>>(taqWc, 256, 256, 256, taqWT, 256, 256);
  k_transpose<<<tg(256,256), b256, 0, stream>>>(takWc, 256, 256, 256, takWT, 256, 256);
  k_transpose<<<tg(256,256), b256, 0, stream>>>(tavWc, 256, 256, 256, tavWT, 256, 256);
  k_transpose<<<tg(256,256), b256, 0, stream>>>(f1Wc, 256, 256, 256, f1WT, 256, 256);
  k_transpose<<<tg(256,256), b256, 0, stream>>>(f2Wc, 256, 256, 256, f2WT, 256, 256);
  k_transpose<<<tg(256,256), b256, 0, stream>>>(aggWc, 256, 256, 256, aggWT, 256, 256);
  k_transpose<<<tg(288,256), b256, 0, stream>>>(saqWc, 256, 288, 256, saqWT, 288, 288);
  k_transpose<<<tg(288,256), b256, 0, stream>>>(sakWc, 256, 288, 256, sakWT, 288, 288);
  k_transpose<<<tg(256,256), b256, 0, stream>>>(savWc, 256, 256, 256, savWT, 256, 256);
  k_transpose<<<tg(256,256), b256, 0, stream>>>(sf1Wc, 256, 256, 256, sf1WT, 256, 256);
  k_transpose<<<tg(256,256), b256, 0, stream>>>(sf2Wc, 256, 256, 256, sf2WT, 256, 256);

  k_gate<<<4096, b256, 0, stream>>>(mf, gWc, gbc, gate, dt);
  k_checkf32<<<256, b256, 0, stream>>>(gate, (size_t)4096*158, 1, flags);

  for (int c = 0; c < NCHUNK; c++){
    const float* gate_c = gate + (size_t)c*NC*158;
    float*       z_c    = z    + (size_t)c*NC*256;
    size_t rowoff = (size_t)c*MC;
    int dbg = (c == 0);

    k_ag<<<(MC*160)/256, b256, 0, stream>>>(sf, rowoff, gate_c, Ag, MC*160, dt);
    if (dbg) k_checkbf<<<256, b256, 0, stream>>>(Ag, (size_t)MC*160, 2, flags);
    k_gemm<128,128><<<dim3(MC/128, 2), b256, 0, stream>>>(Ag,160, projWT,160, C0,256,
        projbc, nullptr,0, pec, 1.f, 0, 160);
    if (dbg) k_checkbf<<<256, b256, 0, stream>>>(C0, (size_t)MC*256, 3, flags);
    k_ln<<<MC/4, b256, 0, stream>>>(C0, n1gc, n1bc, C1);
    if (dbg) k_checkbf<<<256, b256, 0, stream>>>(C1, (size_t)MC*256, 4, flags);
    k_gemm<128,128><<<dim3(MC/128, 2), b256, 0, stream>>>(C1,256, taqWT,256, C0,256,
        nullptr, nullptr,0, nullptr, 1.f, 0, 256);
    if (dbg) k_checkbf<<<256, b256, 0, stream>>>(C0, (size_t)MC*256, 5, flags);
    k_gemm<128,128><<<dim3(MC/128, 2), b256, 0, stream>>>(C1,256, takWT,256, C2,256,
        nullptr, nullptr,0, nullptr, 1.f, 0, 256);
    if (dbg) k_checkbf<<<256, b256, 0, stream>>>(C2, (size_t)MC*256, 6, flags);
    k_gemm<128,128><<<dim3(MC/128, 2), b256, 0, stream>>>(C1,256, tavWT,256, C3,256,
        nullptr, nullptr,0, nullptr, 1.f, 0, 256);
    if (dbg) k_checkbf<<<256, b256, 0, stream>>>(C3, (size_t)MC*256, 7, flags);
    k_tattn<<<NC*4, b64, 0, stream>>>(C0, C2, C3, C1);
    if (dbg) k_checkbf<<<256, b256, 0, stream>>>(C1, (size_t)MC*256, 8, flags);
    k_ln<<<MC/4, b256, 0, stream>>>(C1, n2gc, n2bc, C0);
    if (dbg) k_checkbf<<<256, b256, 0, stream>>>(C0, (size_t)MC*256, 9, flags);
    k_gemm<128,128><<<dim3(MC/128, 2), b256, 0, stream>>>(C0,256, f1WT,256, C2,256,
        f1bc, nullptr,0, nullptr, 1.f, 1, 256);
    if (dbg) k_checkbf<<<256, b256, 0, stream>>>(C2, (size_t)MC*256, 10, flags);
    k_gemm<128,128><<<dim3(MC/128, 2), b256, 0, stream>>>(C2,256, f2WT,256, C3,256,
        f2bc, C1,256, nullptr, 1.f, 0, 256);
    if (dbg) k_checkbf<<<256, b256, 0, stream>>>(C3, (size_t)MC*256, 11, flags);
    k_gemm<128,128><<<dim3(MC/128, 2), b256, 0, stream>>>(C3,256, aggWT,256, C0,256,
        nullptr, nullptr,0, nullptr, 1.f, 0, 256);
    if (dbg) k_checkbf<<<256, b256, 0, stream>>>(C0, (size_t)MC*256, 12, flags);
    k_lamz<<<NC, b256, 0, stream>>>(C0, C3, z_c);
    if (dbg) k_checkf32<<<256, b256, 0, stream>>>(z_c, (size_t)NC*256, 13, flags);
  }
  k_checkf32<<<256, b256, 0, stream>>>(z, (size_t)4096*256, 14, flags);

  k_prep<<<4096, b64, 0, stream>>>(z, ids, embc, sn1gc, sn1bc, sn2gc, sn2bc, zn, qkin);
  k_checkbf<<<256, b256, 0, stream>>>(zn, (size_t)4096*256, 15, flags);
  k_checkbf<<<256, b256, 0, stream>>>(qkin, (size_t)4096*288, 16, flags);
  k_gemm<128,128><<<dim3(32,2,1), b256, 0, stream>>>(qkin,288, saqWT,288, q2,256,
      nullptr, nullptr,0, nullptr, 1.f, 0, 288);
  k_gemm<128,128><<<dim3(32,2,1), b256, 0, stream>>>(qkin,288, sakWT,288, k2,256,
      nullptr, nullptr,0, nullptr, 1.f, 0, 288);
  k_gemm<128,128><<<dim3(32,2,1), b256, 0, stream>>>(zn,256, savWT,256, v2,256,
      nullptr, nullptr,0, nullptr, 1.f, 0, 256);
  k_checkbf<<<256, b256, 0, stream>>>(q2, (size_t)4096*256, 17, flags);
  k_checkbf<<<256, b256, 0, stream>>>(k2, (size_t)4096*256, 18, flags);
  k_checkbf<<<256, b256, 0, stream>>>(v2, (size_t)4096*256, 19, flags);

  for (int h = 0; h < 4; h++){
    k_transpose<<<dim3(128,2), b256, 0, stream>>>(v2 + h*64, 256, 4096, 64, v2Th, 4096, 4096);
    if (h == 0) k_checkbf<<<256, b256, 0, stream>>>(v2Th, (size_t)64*4096, 20, flags);
    for (int rb = 0; rb < NSB; rb++){
      const ushort* q2b = q2 + (size_t)rb*SB*256 + h*64;
      k_gemm<128,128><<<dim3(SB/128, 32), b256, 0, stream>>>(q2b,256, k2 + h*64,256,
          scoresB,4096, nullptr, nullptr,0, nullptr, 0.125f, 0, 64);
      if (h == 0 && rb == 0) k_checkbf<<<256, b256, 0, stream>>>(scoresB, (size_t)SB*4096, 21, flags);
      k_softmax4096<<<SB, b256, 0, stream>>>(scoresB);
      if (h == 0 && rb == 0) k_checkbf<<<256, b256, 0, stream>>>(scoresB, (size_t)SB*4096, 22, flags);
      k_gemm<256,64><<<dim3(SB/256, 1), b256, 0, stream>>>(scoresB,4096, v2Th,4096,
          xt2 + (size_t)rb*SB*256 + h*64,256, nullptr, zn + (size_t)rb*SB*256 + h*64,256,
          nullptr, 1.f, 0, 4096);
    }
  }
  k_checkbf<<<256, b256, 0, stream>>>(xt2, (size_t)4096*256, 23, flags);

  k_ln<<<1024, b256, 0, stream>>>(xt2, sn3gc, sn3bc, n3);
  k_checkbf<<<256, b256, 0, stream>>>(n3, (size_t)4096*256, 24, flags);
  k_gemm<128,128><<<dim3(32,2,1), b256, 0, stream>>>(n3,256, sf1WT,256, h2,256,
      sf1bc, nullptr,0, nullptr, 1.f, 1, 256);
  k_checkbf<<<256, b256, 0, stream>>>(h2, (size_t)4096*256, 25, flags);
  k_gemm<128,128><<<dim3(32,2,1), b256, 0, stream>>>(h2,256, sf2WT,256, xv,256,
      sf2bc, xt2,256, nullptr, 1.f, 0, 256);
  k_checkbf<<<256, b256, 0, stream>>>(xv, (size_t)4096*256, 26, flags);
  k_decode<<<4096, b64, 0, stream>>>(xv, decWc, decbc, d_out, dt);
  k_checkout<<<16, b256, 0, stream>>>(d_out, 4096, 27, flags, dt);
  k_finalize<<<16, b256, 0, stream>>>(d_out, 4096, flags, dt);
}

// Round 5
// 1895.422 us; speedup vs baseline: 2.4890x; 2.4890x over previous
//
#include <hip/hip_runtime.h>
#include <math.h>

typedef unsigned int uint32;
typedef unsigned short ushort;

typedef __bf16 bf16x8 __attribute__((ext_vector_type(8)));
typedef float f32x4 __attribute__((ext_vector_type(4)));

#define DEV static __device__ __forceinline__

DEV float bf2f(ushort u){ return __builtin_bit_cast(float, ((uint32)u) << 16); }
DEV ushort f2bf(float f){
  uint32 i = __builtin_bit_cast(uint32, f);
  uint32 r = i + 0x7fffu + ((i >> 16) & 1u);   // RNE
  return (ushort)(r >> 16);
}
DEV float wsum(float v){
  #pragma unroll
  for (int off = 32; off > 0; off >>= 1) v += __shfl_xor(v, off);
  return v;
}

// ================= dtype detect (inputs proven fp32 in R4; keep adaptive) ==========
__global__ void k_detect(const ushort* pe, const ushort* n1g, int* dt){
  if (threadIdx.x==0 && blockIdx.x==0){
    int isb = (pe[1]==0x3F80u && n1g[0]==0x3F80u) ? 1 : 0;
    *dt = isb ? 1 : 0;   // default fp32 unless bf16 signature
  }
}

// ================= batched convert: 33 float inputs -> bf16, ONE launch ============
struct CvtArgs { const void* src[33]; ushort* dst[33]; int n[33]; };
__global__ __launch_bounds__(256) void k_cvtbatch(CvtArgs a, const int* dtp){
  int z = blockIdx.y;
  int i = blockIdx.x*256 + threadIdx.x;
  if (i >= a.n[z]) return;
  int sdt = *dtp;
  a.dst[z][i] = sdt ? ((const ushort*)a.src[z])[i] : f2bf(((const float*)a.src[z])[i]);
}

// ================= batched transpose: 12 weights, ONE launch =======================
// dst[c][r] = (r<R ? src[r*ld_src+c] : 0), c<C, r<RP
struct TrArgs { const ushort* src[12]; ushort* dst[12]; int ldsrc[12]; int R[12]; int C[12]; int lddst[12]; int RP[12]; };
__global__ __launch_bounds__(256) void k_trbatch(TrArgs a){
  int z = blockIdx.z;
  __shared__ ushort tile[32][33];
  int tx = threadIdx.x & 31, ty = threadIdx.x >> 5;
  int rb = blockIdx.x * 32, cb = blockIdx.y * 32;
  const ushort* src = a.src[z];
  int ld_src = a.ldsrc[z], R = a.R[z], C = a.C[z];
  #pragma unroll
  for (int i = 0; i < 4; i++){
    int r = rb + ty + i*8, c = cb + tx;
    ushort v = 0;
    if (r < R && c < C) v = src[(size_t)r*ld_src + c];
    tile[ty + i*8][tx] = v;
  }
  __syncthreads();
  ushort* dst = a.dst[z];
  int ld_dst = a.lddst[z], RP = a.RP[z];
  #pragma unroll
  for (int i = 0; i < 4; i++){
    int c = cb + ty + i*8, r = rb + tx;
    if (c < C && r < RP) dst[(size_t)c*ld_dst + r] = tile[tx][ty + i*8];
  }
}

// single transpose (for v2 -> vT)
__global__ __launch_bounds__(256) void k_transpose(const ushort* __restrict__ src, int ld_src,
    int R, int C, ushort* __restrict__ dst, int ld_dst, int RP)
{
  __shared__ ushort tile[32][33];
  int tx = threadIdx.x & 31, ty = threadIdx.x >> 5;
  int rb = blockIdx.x * 32, cb = blockIdx.y * 32;
  #pragma unroll
  for (int i = 0; i < 4; i++){
    int r = rb + ty + i*8, c = cb + tx;
    ushort v = 0;
    if (r < R && c < C) v = src[(size_t)r*ld_src + c];
    tile[ty + i*8][tx] = v;
  }
  __syncthreads();
  #pragma unroll
  for (int i = 0; i < 4; i++){
    int c = cb + ty + i*8, r = rb + tx;
    if (c < C && r < RP) dst[(size_t)c*ld_dst + r] = tile[tx][ty + i*8];
  }
}

// ================= gate = 158 * softmax(mkt @ gate_W + gate_b) =====================
__global__ __launch_bounds__(256) void k_gate(const void* __restrict__ mfv,
    const ushort* __restrict__ gW, const ushort* __restrict__ gb, float* __restrict__ gate,
    const int* dtp)
{
  int n = blockIdx.x, tid = threadIdx.x;
  __shared__ int sdt;
  __shared__ float mkt[64];
  __shared__ float red[256];
  if (tid == 0) sdt = *dtp;
  __syncthreads();
  if (tid < 64){
    size_t idx = ((size_t)n*64 + 63)*64 + tid;
    mkt[tid] = sdt ? bf2f(((const ushort*)mfv)[idx]) : ((const float*)mfv)[idx];
  }
  __syncthreads();
  float lg = -1e30f;
  if (tid < 158){
    float a = bf2f(gb[tid]);
    #pragma unroll 8
    for (int d = 0; d < 64; d++) a += mkt[d] * bf2f(gW[d*158 + tid]);
    lg = a;
  }
  red[tid] = lg; __syncthreads();
  for (int s = 128; s > 0; s >>= 1){ if (tid < s) red[tid] = fmaxf(red[tid], red[tid+s]); __syncthreads(); }
  float mx = red[0]; __syncthreads();
  float p = (tid < 158) ? __expf(lg - mx) : 0.f;
  red[tid] = p; __syncthreads();
  for (int s = 128; s > 0; s >>= 1){ if (tid < s) red[tid] += red[tid+s]; __syncthreads(); }
  float inv = 158.f / red[0];
  if (tid < 158) gate[(size_t)n*158 + tid] = p * inv;
}

// Ag[row][d] = sf[rowoff+row][d] * gate_c[row>>6][d]; K padded 158->160
__global__ __launch_bounds__(256) void k_ag(const void* __restrict__ sfv, size_t rowoff,
    const float* __restrict__ gate_c, ushort* __restrict__ Ag, int total, const int* dtp)
{
  __shared__ int sdt;
  if (threadIdx.x == 0) sdt = *dtp;
  __syncthreads();
  int idx = blockIdx.x*256 + threadIdx.x;
  if (idx >= total) return;
  int row = idx / 160;
  int d = idx - row*160;
  float v = 0.f;
  if (d < 158){
    int n = row >> 6;
    size_t si = (rowoff + (size_t)row)*158 + d;
    float s = sdt ? bf2f(((const ushort*)sfv)[si]) : ((const float*)sfv)[si];
    v = s * gate_c[(size_t)n*158 + d];
  }
  Ag[idx] = f2bf(v);
}

// ================= generic bf16 MFMA GEMM ==========================================
template<int BM, int BN>
__global__ __launch_bounds__(256) void k_gemm(
    const ushort* __restrict__ A, int lda,
    const ushort* __restrict__ WT, int ldw,
    ushort* __restrict__ C, int ldc,
    const ushort* __restrict__ bias,
    const ushort* __restrict__ resid, int ldr,
    const ushort* __restrict__ pe,
    float scale, int relu, int K)
{
  __shared__ ushort As[BM*40];
  __shared__ ushort Bs[BN*40];

  const int tid = threadIdx.x;
  const int wave = tid >> 6, lane = tid & 63;
  const int quad = lane >> 4, l16 = lane & 15;
  constexpr int WC = BN/64;
  const int wr = wave / WC, wc = wave % WC;
  const int m0 = blockIdx.x * BM, n0 = blockIdx.y * BN;

  f32x4 acc[4][4];
  #pragma unroll
  for (int i = 0; i < 4; i++)
    #pragma unroll
    for (int j = 0; j < 4; j++)
      acc[i][j] = f32x4{0.f, 0.f, 0.f, 0.f};

  for (int k0 = 0; k0 < K; k0 += 32){
    __syncthreads();
    #pragma unroll
    for (int i = 0; i < BM/64; i++){
      int ch = tid + i*256;
      int r = ch >> 2, cw = (ch & 3)*8;
      *reinterpret_cast<uint4*>(&As[r*40 + cw]) =
        *reinterpret_cast<const uint4*>(A + (size_t)(m0+r)*lda + k0 + cw);
    }
    #pragma unroll
    for (int i = 0; i < BN/64; i++){
      int ch = tid + i*256;
      int r = ch >> 2, cw = (ch & 3)*8;
      *reinterpret_cast<uint4*>(&Bs[r*40 + cw]) =
        *reinterpret_cast<const uint4*>(WT + (size_t)(n0+r)*ldw + k0 + cw);
    }
    __syncthreads();
    bf16x8 af[4], bfr[4];
    #pragma unroll
    for (int t = 0; t < 4; t++){
      af[t]  = *reinterpret_cast<const bf16x8*>(&As[(wr*64 + t*16 + l16)*40 + quad*8]);
      bfr[t] = *reinterpret_cast<const bf16x8*>(&Bs[(wc*64 + t*16 + l16)*40 + quad*8]);
    }
    #pragma unroll
    for (int mt = 0; mt < 4; mt++)
      #pragma unroll
      for (int nt = 0; nt < 4; nt++)
        acc[mt][nt] = __builtin_amdgcn_mfma_f32_16x16x32_bf16(af[mt], bfr[nt], acc[mt][nt], 0, 0, 0);
  }

  #pragma unroll
  for (int mt = 0; mt < 4; mt++){
    #pragma unroll
    for (int nt = 0; nt < 4; nt++){
      int col = n0 + wc*64 + nt*16 + l16;
      #pragma unroll
      for (int r = 0; r < 4; r++){
        int row = m0 + wr*64 + mt*16 + quad*4 + r;
        float v = acc[mt][nt][r] * scale;
        if (bias)  v += bf2f(bias[col]);
        if (pe)    v += bf2f(pe[(row & 63)*256 + col]);
        if (relu)  v = fmaxf(v, 0.f);
        if (resid) v += bf2f(resid[(size_t)row*ldr + col]);
        C[(size_t)row*ldc + col] = f2bf(v);
      }
    }
  }
}

// ================= LayerNorm rows of 256 ===========================================
__global__ __launch_bounds__(256) void k_ln(const ushort* __restrict__ x,
    const ushort* __restrict__ g, const ushort* __restrict__ b, ushort* __restrict__ y)
{
  int row = blockIdx.x*4 + (threadIdx.x >> 6);
  int lane = threadIdx.x & 63;
  ushort4 u = *reinterpret_cast<const ushort4*>(x + (size_t)row*256 + lane*4);
  float v0 = bf2f(u.x), v1 = bf2f(u.y), v2 = bf2f(u.z), v3 = bf2f(u.w);
  float s = wsum(v0+v1+v2+v3);
  float q = wsum(v0*v0+v1*v1+v2*v2+v3*v3);
  float mean = s * (1.f/256.f);
  float var  = fmaxf(q * (1.f/256.f) - mean*mean, 0.f);
  float rs = rsqrtf(var + 1e-5f);
  ushort4 gg = *reinterpret_cast<const ushort4*>(g + lane*4);
  ushort4 bb = *reinterpret_cast<const ushort4*>(b + lane*4);
  ushort4 o;
  o.x = f2bf((v0-mean)*rs*bf2f(gg.x) + bf2f(bb.x));
  o.y = f2bf((v1-mean)*rs*bf2f(gg.y) + bf2f(bb.y));
  o.z = f2bf((v2-mean)*rs*bf2f(gg.z) + bf2f(bb.z));
  o.w = f2bf((v3-mean)*rs*bf2f(gg.w) + bf2f(bb.w));
  *reinterpret_cast<ushort4*>(y + (size_t)row*256 + lane*4) = o;
}

// ================= temporal attention per (stock, head) ============================
__global__ __launch_bounds__(64) void k_tattn(
    const ushort* __restrict__ q, const ushort* __restrict__ k,
    const ushort* __restrict__ v, ushort* __restrict__ xnxt)
{
  int n = blockIdx.x >> 2, h = blockIdx.x & 3;
  int lane = threadIdx.x;
  int quad = lane >> 4, l16 = lane & 15;
  __shared__ ushort Pl[64*72];
  __shared__ ushort Vt[64*72];
  size_t base = ((size_t)n*64)*256 + (size_t)h*64;

  f32x4 accs[4][4];
  #pragma unroll
  for (int i = 0; i < 4; i++)
    #pragma unroll
    for (int j = 0; j < 4; j++)
      accs[i][j] = f32x4{0.f, 0.f, 0.f, 0.f};

  #pragma unroll
  for (int ks = 0; ks < 64; ks += 32){
    bf16x8 qf[4], kf[4];
    #pragma unroll
    for (int tt = 0; tt < 4; tt++){
      qf[tt] = *reinterpret_cast<const bf16x8*>(q + base + (size_t)(tt*16 + l16)*256 + ks + quad*8);
      kf[tt] = *reinterpret_cast<const bf16x8*>(k + base + (size_t)(tt*16 + l16)*256 + ks + quad*8);
    }
    #pragma unroll
    for (int mt = 0; mt < 4; mt++)
      #pragma unroll
      for (int nt = 0; nt < 4; nt++)
        accs[mt][nt] = __builtin_amdgcn_mfma_f32_16x16x32_bf16(qf[mt], kf[nt], accs[mt][nt], 0, 0, 0);
  }

  for (int s = 0; s < 64; s++)
    Vt[lane*72 + s] = v[base + (size_t)s*256 + lane];

  #pragma unroll
  for (int mt = 0; mt < 4; mt++){
    #pragma unroll
    for (int r = 0; r < 4; r++){
      float a0 = accs[mt][0][r], a1 = accs[mt][1][r], a2 = accs[mt][2][r], a3 = accs[mt][3][r];
      float mx = fmaxf(fmaxf(a0, a1), fmaxf(a2, a3));
      #pragma unroll
      for (int off = 1; off < 16; off <<= 1) mx = fmaxf(mx, __shfl_xor(mx, off));
      float e0 = __expf(a0-mx), e1 = __expf(a1-mx), e2 = __expf(a2-mx), e3 = __expf(a3-mx);
      float sum = e0+e1+e2+e3;
      #pragma unroll
      for (int off = 1; off < 16; off <<= 1) sum += __shfl_xor(sum, off);
      float inv = 1.f/sum;
      int t = mt*16 + quad*4 + r;
      Pl[t*72 +  0 + l16] = f2bf(e0*inv);
      Pl[t*72 + 16 + l16] = f2bf(e1*inv);
      Pl[t*72 + 32 + l16] = f2bf(e2*inv);
      Pl[t*72 + 48 + l16] = f2bf(e3*inv);
    }
  }
  __syncthreads();

  f32x4 acco[4][4];
  #pragma unroll
  for (int i = 0; i < 4; i++)
    #pragma unroll
    for (int j = 0; j < 4; j++)
      acco[i][j] = f32x4{0.f, 0.f, 0.f, 0.f};

  #pragma unroll
  for (int ks = 0; ks < 64; ks += 32){
    bf16x8 pf[4], vf[4];
    #pragma unroll
    for (int tt = 0; tt < 4; tt++){
      pf[tt] = *reinterpret_cast<const bf16x8*>(&Pl[(tt*16 + l16)*72 + ks + quad*8]);
      vf[tt] = *reinterpret_cast<const bf16x8*>(&Vt[(tt*16 + l16)*72 + ks + quad*8]);
    }
    #pragma unroll
    for (int mt = 0; mt < 4; mt++)
      #pragma unroll
      for (int nt = 0; nt < 4; nt++)
        acco[mt][nt] = __builtin_amdgcn_mfma_f32_16x16x32_bf16(pf[mt], vf[nt], acco[mt][nt], 0, 0, 0);
  }

  #pragma unroll
  for (int mt = 0; mt < 4; mt++)
    #pragma unroll
    for (int nt = 0; nt < 4; nt++)
      #pragma unroll
      for (int r = 0; r < 4; r++){
        int t = mt*16 + quad*4 + r, d = nt*16 + l16;
        size_t g = base + (size_t)t*256 + d;
        xnxt[g] = f2bf(bf2f(xnxt[g]) + acco[mt][nt][r]);
      }
}

// ================= lam = softmax_t(h . h_last); z = sum_t lam * x2 =================
__global__ __launch_bounds__(256) void k_lamz(const ushort* __restrict__ h,
    const ushort* __restrict__ x2, float* __restrict__ z)
{
  int n = blockIdx.x, tid = threadIdx.x, wave = tid >> 6, lane = tid & 63;
  __shared__ float hl[256];
  __shared__ float dotv[64];
  __shared__ float lamv[64];
  hl[tid] = bf2f(h[((size_t)n*64 + 63)*256 + tid]);
  __syncthreads();
  float h0 = hl[lane*4], h1 = hl[lane*4+1], h2 = hl[lane*4+2], h3 = hl[lane*4+3];
  for (int tt = 0; tt < 16; tt++){
    int t = wave*16 + tt;
    ushort4 u = *reinterpret_cast<const ushort4*>(h + ((size_t)n*64 + t)*256 + lane*4);
    float p = bf2f(u.x)*h0 + bf2f(u.y)*h1 + bf2f(u.z)*h2 + bf2f(u.w)*h3;
    p = wsum(p);
    if (lane == 0) dotv[t] = p;
  }
  __syncthreads();
  if (wave == 0){
    float vv = dotv[lane];
    float mx = vv;
    #pragma unroll
    for (int off = 32; off > 0; off >>= 1) mx = fmaxf(mx, __shfl_xor(mx, off));
    float e = __expf(vv - mx);
    float s = wsum(e);
    lamv[lane] = e / s;
  }
  __syncthreads();
  float acc = 0.f;
  for (int t = 0; t < 64; t++) acc += lamv[t] * bf2f(x2[((size_t)n*64 + t)*256 + tid]);
  z[(size_t)n*256 + tid] = acc;
}

// ================= zn = LN(z); en = LN(emb[id]); qkin = [zn, en] ===================
__global__ __launch_bounds__(64) void k_prep(const float* __restrict__ z,
    const int* __restrict__ ids, const ushort* __restrict__ emb,
    const ushort* __restrict__ g1, const ushort* __restrict__ b1,
    const ushort* __restrict__ g2, const ushort* __restrict__ b2,
    ushort* __restrict__ zn, ushort* __restrict__ qkin)
{
  int n = blockIdx.x, lane = threadIdx.x;
  float4 v = *reinterpret_cast<const float4*>(z + (size_t)n*256 + lane*4);
  float s = wsum(v.x+v.y+v.z+v.w);
  float q = wsum(v.x*v.x+v.y*v.y+v.z*v.z+v.w*v.w);
  float mean = s*(1.f/256.f);
  float var = fmaxf(q*(1.f/256.f) - mean*mean, 0.f);
  float rs = rsqrtf(var + 1e-5f);
  ushort4 gg = *reinterpret_cast<const ushort4*>(g1 + lane*4);
  ushort4 bb = *reinterpret_cast<const ushort4*>(b1 + lane*4);
  ushort4 o;
  o.x = f2bf((v.x-mean)*rs*bf2f(gg.x) + bf2f(bb.x));
  o.y = f2bf((v.y-mean)*rs*bf2f(gg.y) + bf2f(bb.y));
  o.z = f2bf((v.z-mean)*rs*bf2f(gg.z) + bf2f(bb.z));
  o.w = f2bf((v.w-mean)*rs*bf2f(gg.w) + bf2f(bb.w));
  *reinterpret_cast<ushort4*>(zn + (size_t)n*256 + lane*4) = o;
  *reinterpret_cast<ushort4*>(qkin + (size_t)n*288 + lane*4) = o;
  int id = ids[n];
  float ev = (lane < 32) ? bf2f(emb[(size_t)id*32 + lane]) : 0.f;
  float se = ev, sq = ev*ev;
  #pragma unroll
  for (int off = 1; off < 32; off <<= 1){ se += __shfl_xor(se, off); sq += __shfl_xor(sq, off); }
  if (lane < 32){
    float m2 = se*(1.f/32.f);
    float va = fmaxf(sq*(1.f/32.f) - m2*m2, 0.f);
    float r2 = rsqrtf(va + 1e-5f);
    qkin[(size_t)n*288 + 256 + lane] = f2bf((ev-m2)*r2*bf2f(g2[lane]) + bf2f(b2[lane]));
  }
}

// ================= flash cross-sectional attention =================================
// grid (64 row-blocks, 4 heads), 256 thr. qk = q2|k2 (4096 x 512, ld 512),
// vT = v2^T (256 x 4096). xt2 = zn + softmax(q k^T / 8) v
__global__ __launch_bounds__(256) void k_xattn(
    const ushort* __restrict__ qk, const ushort* __restrict__ vT,
    const ushort* __restrict__ zn, ushort* __restrict__ xt2)
{
  int rb = blockIdx.x, h = blockIdx.y;
  int tid = threadIdx.x, wave = tid >> 6, lane = tid & 63;
  int quad = lane >> 4, l16 = lane & 15;
  int q0 = rb*64 + wave*16;

  bf16x8 qf[2];
  #pragma unroll
  for (int s = 0; s < 2; s++)
    qf[s] = *reinterpret_cast<const bf16x8*>(qk + (size_t)(q0 + l16)*512 + h*64 + s*32 + quad*8);

  float m[4]  = {-1e30f,-1e30f,-1e30f,-1e30f};
  float l[4]  = {0.f,0.f,0.f,0.f};
  f32x4 acc[4];
  #pragma unroll
  for (int nd = 0; nd < 4; nd++) acc[nd] = f32x4{0.f,0.f,0.f,0.f};

  __shared__ ushort Pl[4][16*72];

  for (int kt = 0; kt < 64; kt++){
    int kb = kt*64;
    f32x4 s4[4];
    #pragma unroll
    for (int nt = 0; nt < 4; nt++){
      f32x4 a = f32x4{0.f,0.f,0.f,0.f};
      #pragma unroll
      for (int s = 0; s < 2; s++){
        bf16x8 kf = *reinterpret_cast<const bf16x8*>(
            qk + (size_t)(kb + nt*16 + l16)*512 + 256 + h*64 + s*32 + quad*8);
        a = __builtin_amdgcn_mfma_f32_16x16x32_bf16(qf[s], kf, a, 0, 0, 0);
      }
      s4[nt] = a;
    }
    float alpha[4];
    #pragma unroll
    for (int r = 0; r < 4; r++){
      float v0 = s4[0][r]*0.125f, v1 = s4[1][r]*0.125f, v2 = s4[2][r]*0.125f, v3 = s4[3][r]*0.125f;
      float mx = fmaxf(fmaxf(v0,v1), fmaxf(v2,v3));
      #pragma unroll
      for (int off = 1; off < 16; off <<= 1) mx = fmaxf(mx, __shfl_xor(mx, off));
      float mnew = fmaxf(m[r], mx);
      alpha[r] = __expf(m[r] - mnew);
      float e0 = __expf(v0-mnew), e1 = __expf(v1-mnew), e2 = __expf(v2-mnew), e3 = __expf(v3-mnew);
      float ps = e0+e1+e2+e3;
      #pragma unroll
      for (int off = 1; off < 16; off <<= 1) ps += __shfl_xor(ps, off);
      l[r] = l[r]*alpha[r] + ps;
      m[r] = mnew;
      int t = quad*4 + r;
      Pl[wave][t*72 +  0 + l16] = f2bf(e0);
      Pl[wave][t*72 + 16 + l16] = f2bf(e1);
      Pl[wave][t*72 + 32 + l16] = f2bf(e2);
      Pl[wave][t*72 + 48 + l16] = f2bf(e3);
    }
    #pragma unroll
    for (int nd = 0; nd < 4; nd++)
      #pragma unroll
      for (int r = 0; r < 4; r++)
        acc[nd][r] *= alpha[r];
    __syncthreads();
    #pragma unroll
    for (int s = 0; s < 2; s++){
      bf16x8 pf = *reinterpret_cast<const bf16x8*>(&Pl[wave][l16*72 + s*32 + quad*8]);
      #pragma unroll
      for (int nd = 0; nd < 4; nd++){
        bf16x8 vf = *reinterpret_cast<const bf16x8*>(
            vT + (size_t)(h*64 + nd*16 + l16)*4096 + kb + s*32 + quad*8);
        acc[nd] = __builtin_amdgcn_mfma_f32_16x16x32_bf16(pf, vf, acc[nd], 0, 0, 0);
      }
    }
    __syncthreads();
  }

  #pragma unroll
  for (int nd = 0; nd < 4; nd++)
    #pragma unroll
    for (int r = 0; r < 4; r++){
      int row = q0 + quad*4 + r;
      int col = h*64 + nd*16 + l16;
      float val = acc[nd][r] / l[r] + bf2f(zn[(size_t)row*256 + col]);
      xt2[(size_t)row*256 + col] = f2bf(val);
    }
}

// ================= out[n] = xv[n,:] . decW + decb ==================================
__global__ __launch_bounds__(64) void k_decode(const ushort* __restrict__ xv,
    const ushort* __restrict__ dW, const ushort* __restrict__ db, void* out, const int* dtp)
{
  int n = blockIdx.x, lane = threadIdx.x;
  ushort4 u = *reinterpret_cast<const ushort4*>(xv + (size_t)n*256 + lane*4);
  ushort4 w = *reinterpret_cast<const ushort4*>(dW + lane*4);
  float acc = bf2f(u.x)*bf2f(w.x) + bf2f(u.y)*bf2f(w.y) + bf2f(u.z)*bf2f(w.z) + bf2f(u.w)*bf2f(w.w);
  acc = wsum(acc);
  if (lane == 0){
    float r = acc + bf2f(db[0]);
    if (*dtp) ((ushort*)out)[n] = f2bf(r);
    else      ((float*)out)[n]  = r;
  }
}

extern "C" void kernel_launch(void* const* d_in, const int* in_sizes, int n_in,
                              void* d_out, int out_size, void* d_ws, size_t ws_size,
                              hipStream_t stream)
{
  (void)in_sizes; (void)n_in; (void)out_size;
  const int*  ids = (const int*)d_in[0];
  const void* sf  = d_in[1];
  const void* mf  = d_in[2];

  auto padsz = [](size_t b)->size_t{ return (b + 255) & ~(size_t)255; };
  size_t fixedB = padsz((size_t)4096*158*4) + padsz((size_t)4096*256*4)
                + 6*padsz((size_t)4096*256*2)            // zn,v2,xt2,n3,h2,xv
                + padsz((size_t)4096*512*2)              // q2k2
                + padsz((size_t)256*4096*2)              // vT
                + padsz((size_t)4096*288*2)              // qkin
                + (size_t)4*1024*1024;                   // weights + slop
  auto tierB = [&](int NCp)->size_t{
    size_t MCp = (size_t)NCp*64;
    return fixedB + 4*padsz(MCp*256*2) + padsz(MCp*160*2);
  };
  int NC = 64;
  if      (tierB(4096) <= ws_size) NC = 4096;
  else if (tierB(1024) <= ws_size) NC = 1024;
  else if (tierB(256)  <= ws_size) NC = 256;
  const int NCHUNK = 4096 / NC;
  const int MC = NC * 64;

  char* ws = (char*)d_ws;
  size_t off = 0;
  auto alloc = [&](size_t bytes)->char*{ char* p = ws + off; off += (bytes + 255) & ~(size_t)255; return p; };
  int* dt = (int*)alloc(256);
  ushort* C0 = (ushort*)alloc((size_t)MC*256*2);
  ushort* C1 = (ushort*)alloc((size_t)MC*256*2);
  ushort* C2 = (ushort*)alloc((size_t)MC*256*2);
  ushort* C3 = (ushort*)alloc((size_t)MC*256*2);
  ushort* Ag = (ushort*)alloc((size_t)MC*160*2);
  float*  gate = (float*)alloc((size_t)4096*158*4);
  float*  z    = (float*)alloc((size_t)4096*256*4);
  ushort* zn   = (ushort*)alloc((size_t)4096*256*2);
  ushort* q2k2 = (ushort*)alloc((size_t)4096*512*2);
  ushort* v2   = (ushort*)alloc((size_t)4096*256*2);
  ushort* vT   = (ushort*)alloc((size_t)256*4096*2);
  ushort* xt2  = (ushort*)alloc((size_t)4096*256*2);
  ushort* n3   = (ushort*)alloc((size_t)4096*256*2);
  ushort* h2   = (ushort*)alloc((size_t)4096*256*2);
  ushort* xv   = (ushort*)alloc((size_t)4096*256*2);
  ushort* qkin = (ushort*)alloc((size_t)4096*288*2);

  auto cvalloc = [&](int n)->ushort*{ return (ushort*)alloc((size_t)n*2); };
  ushort* gWc   = cvalloc(64*158);
  ushort* gbc   = cvalloc(158);
  ushort* embc  = cvalloc(256*32);
  ushort* projWc= cvalloc(158*256);
  ushort* projbc= cvalloc(256);
  ushort* pec   = cvalloc(100*256);
  ushort* taqWc = cvalloc(65536);
  ushort* takWc = cvalloc(65536);
  ushort* tavWc = cvalloc(65536);
  ushort* n1gc  = cvalloc(256);
  ushort* n1bc  = cvalloc(256);
  ushort* n2gc  = cvalloc(256);
  ushort* n2bc  = cvalloc(256);
  ushort* f1Wc  = cvalloc(65536);
  ushort* f1bc  = cvalloc(256);
  ushort* f2Wc  = cvalloc(65536);
  ushort* f2bc  = cvalloc(256);
  ushort* aggWc = cvalloc(65536);
  ushort* saqWc = cvalloc(288*256);
  ushort* sakWc = cvalloc(288*256);
  ushort* savWc = cvalloc(65536);
  ushort* sn1gc = cvalloc(256);
  ushort* sn1bc = cvalloc(256);
  ushort* sn2gc = cvalloc(32);
  ushort* sn2bc = cvalloc(32);
  ushort* sn3gc = cvalloc(256);
  ushort* sn3bc = cvalloc(256);
  ushort* sf1Wc = cvalloc(65536);
  ushort* sf1bc = cvalloc(256);
  ushort* sf2Wc = cvalloc(65536);
  ushort* sf2bc = cvalloc(256);
  ushort* decWc = cvalloc(256);
  ushort* decbc = cvalloc(1);
  ushort* projWT = cvalloc(256*160);
  ushort* taqWT  = cvalloc(65536);
  ushort* takWT  = cvalloc(65536);
  ushort* tavWT  = cvalloc(65536);
  ushort* f1WT   = cvalloc(65536);
  ushort* f2WT   = cvalloc(65536);
  ushort* aggWT  = cvalloc(65536);
  ushort* savWT  = cvalloc(65536);
  ushort* sf1WT  = cvalloc(65536);
  ushort* sf2WT  = cvalloc(65536);
  ushort* qk2WT  = cvalloc(512*288);   // saqWT rows 0..255, sakWT rows 256..511

  dim3 b256(256), b64(64);

  k_detect<<<1, 64, 0, stream>>>((const ushort*)d_in[8], (const ushort*)d_in[12], dt);

  // ---- ONE batched convert ----
  CvtArgs ca;
  int ci = 0;
  auto addcv = [&](int idx, ushort* dst, int n){ ca.src[ci]=d_in[idx]; ca.dst[ci]=dst; ca.n[ci]=n; ci++; };
  addcv(3,  gWc,   64*158);  addcv(4,  gbc,   158);     addcv(5,  embc,  256*32);
  addcv(6,  projWc,158*256); addcv(7,  projbc,256);     addcv(8,  pec,   100*256);
  addcv(9,  taqWc, 65536);   addcv(10, takWc, 65536);   addcv(11, tavWc, 65536);
  addcv(12, n1gc,  256);     addcv(13, n1bc,  256);     addcv(14, n2gc,  256);
  addcv(15, n2bc,  256);     addcv(16, f1Wc,  65536);   addcv(17, f1bc,  256);
  addcv(18, f2Wc,  65536);   addcv(19, f2bc,  256);     addcv(20, aggWc, 65536);
  addcv(21, saqWc, 288*256); addcv(22, sakWc, 288*256); addcv(23, savWc, 65536);
  addcv(24, sn1gc, 256);     addcv(25, sn1bc, 256);     addcv(26, sn2gc, 32);
  addcv(27, sn2bc, 32);      addcv(28, sn3gc, 256);     addcv(29, sn3bc, 256);
  addcv(30, sf1Wc, 65536);   addcv(31, sf1bc, 256);     addcv(32, sf2Wc, 65536);
  addcv(33, sf2bc, 256);     addcv(34, decWc, 256);     addcv(35, decbc, 1);
  k_cvtbatch<<<dim3(288, 33), b256, 0, stream>>>(ca, dt);

  // ---- ONE batched weight transpose (WT layout = N x K, K zero-padded) ----
  TrArgs ta;
  int ti = 0;
  auto addtr = [&](const ushort* src, int ldsrc, int R, int C, ushort* dst, int lddst, int RP){
    ta.src[ti]=src; ta.ldsrc[ti]=ldsrc; ta.R[ti]=R; ta.C[ti]=C; ta.dst[ti]=dst; ta.lddst[ti]=lddst; ta.RP[ti]=RP; ti++;
  };
  addtr(projWc, 256, 158, 256, projWT, 160, 160);
  addtr(taqWc,  256, 256, 256, taqWT,  256, 256);
  addtr(takWc,  256, 256, 256, takWT,  256, 256);
  addtr(tavWc,  256, 256, 256, tavWT,  256, 256);
  addtr(f1Wc,   256, 256, 256, f1WT,   256, 256);
  addtr(f2Wc,   256, 256, 256, f2WT,   256, 256);
  addtr(aggWc,  256, 256, 256, aggWT,  256, 256);
  addtr(saqWc,  256, 288, 256, qk2WT,            288, 288);
  addtr(sakWc,  256, 288, 256, qk2WT + 256*288,  288, 288);
  addtr(savWc,  256, 256, 256, savWT,  256, 256);
  addtr(sf1Wc,  256, 256, 256, sf1WT,  256, 256);
  addtr(sf2Wc,  256, 256, 256, sf2WT,  256, 256);
  k_trbatch<<<dim3(9, 8, 12), b256, 0, stream>>>(ta);

  k_gate<<<4096, b256, 0, stream>>>(mf, gWc, gbc, gate, dt);

  // ---- temporal pipeline ----
  for (int c = 0; c < NCHUNK; c++){
    const float* gate_c = gate + (size_t)c*NC*158;
    float*       z_c    = z    + (size_t)c*NC*256;
    size_t rowoff = (size_t)c*MC;

    k_ag<<<(MC*160)/256, b256, 0, stream>>>(sf, rowoff, gate_c, Ag, MC*160, dt);
    k_gemm<128,128><<<dim3(MC/128, 2), b256, 0, stream>>>(Ag,160, projWT,160, C0,256,
        projbc, nullptr,0, pec, 1.f, 0, 160);
    k_ln<<<MC/4, b256, 0, stream>>>(C0, n1gc, n1bc, C1);
    k_gemm<128,128><<<dim3(MC/128, 2), b256, 0, stream>>>(C1,256, taqWT,256, C0,256,
        nullptr, nullptr,0, nullptr, 1.f, 0, 256);
    k_gemm<128,128><<<dim3(MC/128, 2), b256, 0, stream>>>(C1,256, takWT,256, C2,256,
        nullptr, nullptr,0, nullptr, 1.f, 0, 256);
    k_gemm<128,128><<<dim3(MC/128, 2), b256, 0, stream>>>(C1,256, tavWT,256, C3,256,
        nullptr, nullptr,0, nullptr, 1.f, 0, 256);
    k_tattn<<<NC*4, b64, 0, stream>>>(C0, C2, C3, C1);
    k_ln<<<MC/4, b256, 0, stream>>>(C1, n2gc, n2bc, C0);
    k_gemm<128,128><<<dim3(MC/128, 2), b256, 0, stream>>>(C0,256, f1WT,256, C2,256,
        f1bc, nullptr,0, nullptr, 1.f, 1, 256);
    k_gemm<128,128><<<dim3(MC/128, 2), b256, 0, stream>>>(C2,256, f2WT,256, C3,256,
        f2bc, C1,256, nullptr, 1.f, 0, 256);
    k_gemm<128,128><<<dim3(MC/128, 2), b256, 0, stream>>>(C3,256, aggWT,256, C0,256,
        nullptr, nullptr,0, nullptr, 1.f, 0, 256);
    k_lamz<<<NC, b256, 0, stream>>>(C0, C3, z_c);
  }

  // ---- cross-sectional stage ----
  k_prep<<<4096, b64, 0, stream>>>(z, ids, embc, sn1gc, sn1bc, sn2gc, sn2bc, zn, qkin);
  // q2|k2 stacked: (4096 x 512), K=288
  k_gemm<128,128><<<dim3(32,4,1), b256, 0, stream>>>(qkin,288, qk2WT,288, q2k2,512,
      nullptr, nullptr,0, nullptr, 1.f, 0, 288);
  k_gemm<128,128><<<dim3(32,2,1), b256, 0, stream>>>(zn,256, savWT,256, v2,256,
      nullptr, nullptr,0, nullptr, 1.f, 0, 256);
  k_transpose<<<dim3(128, 8), b256, 0, stream>>>(v2, 256, 4096, 256, vT, 4096, 4096);
  k_xattn<<<dim3(64, 4), b256, 0, stream>>>(q2k2, vT, zn, xt2);

  k_ln<<<1024, b256, 0, stream>>>(xt2, sn3gc, sn3bc, n3);
  k_gemm<128,128><<<dim3(32,2,1), b256, 0, stream>>>(n3,256, sf1WT,256, h2,256,
      sf1bc, nullptr,0, nullptr, 1.f, 1, 256);
  k_gemm<128,128><<<dim3(32,2,1), b256, 0, stream>>>(h2,256, sf2WT,256, xv,256,
      sf2bc, xt2,256, nullptr, 1.f, 0, 256);
  k_decode<<<4096, b64, 0, stream>>>(xv, decWc, decbc, d_out, dt);
}